// Round 1
// baseline (1285.461 us; speedup 1.0000x reference)
//
#include <hip/hip_runtime.h>
#include <math.h>

#define B_ 8
#define C_ 256
#define N_ 9216
#define S_ 256
#define K_ 64

// ---------------- fused 1x1conv + BN + ReLU: out[b,o,n] = relu(dot(W[o,:],x[b,:,n])*s + be)
__global__ __launch_bounds__(256) void proj_gemm(
    const float* __restrict__ X, const float* __restrict__ W,
    const float* __restrict__ gg, const float* __restrict__ bb,
    const float* __restrict__ mm, const float* __restrict__ vv,
    float* __restrict__ out, int O)
{
    __shared__ float xs[32][64];   // c x n
    __shared__ float wsT[32][64];  // c x o
    const int b = blockIdx.z;
    const int o0 = blockIdx.y * 64;
    const int n0 = blockIdx.x * 64;
    const int t = threadIdx.x;
    const int tx = t & 15, ty = t >> 4;
    const int nj = t & 63, cb = t >> 6;
    float acc[4][4];
#pragma unroll
    for (int i = 0; i < 4; ++i)
#pragma unroll
        for (int j = 0; j < 4; ++j) acc[i][j] = 0.f;
    const float* Xb = X + (size_t)b * C_ * N_;
    for (int c0 = 0; c0 < C_; c0 += 32) {
#pragma unroll
        for (int k2 = 0; k2 < 8; ++k2) {
            int ci = cb + 4 * k2;
            xs[ci][nj]  = Xb[(size_t)(c0 + ci) * N_ + n0 + nj];
            wsT[ci][nj] = W[(size_t)(o0 + nj) * C_ + c0 + ci];  // nj plays 'o' here (W small, L2-hot)
        }
        __syncthreads();
#pragma unroll
        for (int c = 0; c < 32; ++c) {
            float4 a4 = *(const float4*)&wsT[c][ty * 4];
            float4 b4 = *(const float4*)&xs[c][tx * 4];
            float a[4] = {a4.x, a4.y, a4.z, a4.w};
            float bq[4] = {b4.x, b4.y, b4.z, b4.w};
#pragma unroll
            for (int i = 0; i < 4; ++i)
#pragma unroll
                for (int j = 0; j < 4; ++j)
                    acc[i][j] = fmaf(a[i], bq[j], acc[i][j]);
        }
        __syncthreads();
    }
#pragma unroll
    for (int i = 0; i < 4; ++i) {
        int o = o0 + ty * 4 + i;
        float s  = gg[o] / sqrtf(vv[o] + 1e-5f);
        float be = bb[o] - mm[o] * s;
        float4 r;
        r.x = fmaxf(fmaf(acc[i][0], s, be), 0.f);
        r.y = fmaxf(fmaf(acc[i][1], s, be), 0.f);
        r.z = fmaxf(fmaf(acc[i][2], s, be), 0.f);
        r.w = fmaxf(fmaf(acc[i][3], s, be), 0.f);
        *(float4*)&out[((size_t)b * O + o) * N_ + n0 + tx * 4] = r;
    }
}

// ---------------- softmax over N (rows of length 9216), in place; 36 vals/thread in regs
__global__ __launch_bounds__(256) void softmax_n(float* __restrict__ T)
{
    const int row = blockIdx.x;  // b*S + s
    float* p = T + (size_t)row * N_;
    const int t = threadIdx.x;
    float v[36];
    float mx = -INFINITY;
#pragma unroll
    for (int i = 0; i < 36; ++i) { v[i] = p[t + i * 256]; mx = fmaxf(mx, v[i]); }
    __shared__ float red[256];
    red[t] = mx; __syncthreads();
    for (int s2 = 128; s2 > 0; s2 >>= 1) {
        if (t < s2) red[t] = fmaxf(red[t], red[t + s2]);
        __syncthreads();
    }
    mx = red[0]; __syncthreads();
    float sum = 0.f;
#pragma unroll
    for (int i = 0; i < 36; ++i) { v[i] = __expf(v[i] - mx); sum += v[i]; }
    red[t] = sum; __syncthreads();
    for (int s2 = 128; s2 > 0; s2 >>= 1) {
        if (t < s2) red[t] += red[t + s2];
        __syncthreads();
    }
    float inv = 1.0f / red[0];
#pragma unroll
    for (int i = 0; i < 36; ++i) p[t + i * 256] = v[i] * inv;
}

// ---------------- softmax over S (channels, stride N), in place
__global__ __launch_bounds__(256) void softmax_s(float* __restrict__ R)
{
    const int b = blockIdx.y;
    const int n = blockIdx.x * 256 + threadIdx.x;
    float* p = R + (size_t)b * S_ * N_ + n;
    float mx = -INFINITY;
    for (int s = 0; s < S_; ++s) mx = fmaxf(mx, p[(size_t)s * N_]);
    float sum = 0.f;
    for (int s = 0; s < S_; ++s) sum += __expf(p[(size_t)s * N_] - mx);
    float inv = 1.0f / sum;
    for (int s = 0; s < S_; ++s) p[(size_t)s * N_] = __expf(p[(size_t)s * N_] - mx) * inv;
}

// ---------------- discrib[b,k,s] += sum_{n in chunk} phi[b,k,n] * theta[b,s,n]
__global__ __launch_bounds__(256) void discrib_acc(
    const float* __restrict__ Phi, const float* __restrict__ Th, float* __restrict__ D)
{
    __shared__ float th[S_][33];  // s x n_sub(32), stride-33: conflict-free strided reads
    __shared__ float ph[K_][33];
    const int b = blockIdx.y;
    const int nc0 = blockIdx.x * 256;
    const int t = threadIdx.x;
    const int lane = t & 63;
    const int k0 = (t >> 6) * 16;
    const int ln = t & 31, lr = t >> 5;
    float acc[4][16];
#pragma unroll
    for (int si = 0; si < 4; ++si)
#pragma unroll
        for (int ki = 0; ki < 16; ++ki) acc[si][ki] = 0.f;

    for (int sub = 0; sub < 8; ++sub) {
        const int n0 = nc0 + sub * 32;
        __syncthreads();
#pragma unroll
        for (int i = 0; i < 32; ++i)
            th[lr + 8 * i][ln] = Th[((size_t)b * S_ + lr + 8 * i) * N_ + n0 + ln];
#pragma unroll
        for (int i = 0; i < 8; ++i)
            ph[lr + 8 * i][ln] = Phi[((size_t)b * K_ + lr + 8 * i) * N_ + n0 + ln];
        __syncthreads();
#pragma unroll 4
        for (int n = 0; n < 32; ++n) {
            float tv[4];
#pragma unroll
            for (int si = 0; si < 4; ++si) tv[si] = th[lane + 64 * si][n];
#pragma unroll
            for (int kg = 0; kg < 4; ++kg) {
                float p0 = ph[k0 + 4 * kg + 0][n];
                float p1 = ph[k0 + 4 * kg + 1][n];
                float p2 = ph[k0 + 4 * kg + 2][n];
                float p3 = ph[k0 + 4 * kg + 3][n];
#pragma unroll
                for (int si = 0; si < 4; ++si) {
                    acc[si][4 * kg + 0] = fmaf(tv[si], p0, acc[si][4 * kg + 0]);
                    acc[si][4 * kg + 1] = fmaf(tv[si], p1, acc[si][4 * kg + 1]);
                    acc[si][4 * kg + 2] = fmaf(tv[si], p2, acc[si][4 * kg + 2]);
                    acc[si][4 * kg + 3] = fmaf(tv[si], p3, acc[si][4 * kg + 3]);
                }
            }
        }
    }
#pragma unroll
    for (int si = 0; si < 4; ++si)
#pragma unroll
        for (int ki = 0; ki < 16; ++ki)
            atomicAdd(&D[((size_t)b * K_ + k0 + ki) * S_ + lane + 64 * si], acc[si][ki]);
}

// ---------------- Q_raw[b,n,k] = sum_s D[b,k,s] * rou[b,s,n]
__global__ __launch_bounds__(256) void q_raw(
    const float* __restrict__ D, const float* __restrict__ Rou, float* __restrict__ Qo)
{
    __shared__ float dl[K_ * S_];  // 64KB
    const int b = blockIdx.y;
    const int n0 = blockIdx.x * 256;
    const int t = threadIdx.x;
    const float* Db = D + (size_t)b * K_ * S_;
#pragma unroll
    for (int i = 0; i < 64; ++i) dl[t + 256 * i] = Db[t + 256 * i];
    __syncthreads();
    const int n = n0 + t;
    float acc[64];
#pragma unroll
    for (int k = 0; k < 64; ++k) acc[k] = 0.f;
    const float* Rb = Rou + (size_t)b * S_ * N_ + n;
    for (int sg = 0; sg < 64; ++sg) {
        float r0 = Rb[(size_t)(4 * sg + 0) * N_];
        float r1 = Rb[(size_t)(4 * sg + 1) * N_];
        float r2 = Rb[(size_t)(4 * sg + 2) * N_];
        float r3 = Rb[(size_t)(4 * sg + 3) * N_];
#pragma unroll
        for (int k = 0; k < 64; ++k) {
            float4 d4 = *(const float4*)&dl[k * 256 + 4 * sg];  // broadcast read
            acc[k] = fmaf(d4.x, r0, fmaf(d4.y, r1, fmaf(d4.z, r2, fmaf(d4.w, r3, acc[k]))));
        }
    }
    float* Qrow = Qo + ((size_t)b * N_ + n) * K_;
#pragma unroll
    for (int k = 0; k < 16; ++k) {
        float4 r = make_float4(acc[4 * k], acc[4 * k + 1], acc[4 * k + 2], acc[4 * k + 3]);
        *(float4*)&Qrow[4 * k] = r;
    }
}

// ---------------- norm2[b,k] += sum_{n in chunk} Q[b,n,k]^2
__global__ __launch_bounds__(256) void q_norm2(const float* __restrict__ Q, float* __restrict__ Nrm)
{
    __shared__ float red[256];
    const int b = blockIdx.y, n0 = blockIdx.x * 256;
    const int t = threadIdx.x, lane = t & 63, grp = t >> 6;
    float ss = 0.f;
    for (int i = grp; i < 256; i += 4) {
        float v = Q[((size_t)b * N_ + n0 + i) * K_ + lane];
        ss = fmaf(v, v, ss);
    }
    red[t] = ss;
    __syncthreads();
    if (grp == 0)
        atomicAdd(&Nrm[b * K_ + lane], red[lane] + red[64 + lane] + red[128 + lane] + red[192 + lane]);
}

// ---------------- Q = softmax_k(Q / max(sqrt(norm2),eps)); qsum[b,k] += sum_n Q
__global__ __launch_bounds__(256) void q_final(float* __restrict__ Q,
    const float* __restrict__ Nrm, float* __restrict__ Qs)
{
    __shared__ float red[256];
    const int b = blockIdx.y, n0 = blockIdx.x * 256;
    const int t = threadIdx.x, lane = t & 63, w = t >> 6;
    const float inv = 1.0f / fmaxf(sqrtf(Nrm[b * K_ + lane]), 1e-12f);
    float qs = 0.f;
    for (int i = 0; i < 64; ++i) {
        int n = n0 + 4 * i + w;
        float* p = &Q[((size_t)b * N_ + n) * K_ + lane];
        float v = *p * inv;
        float mx = v;
#pragma unroll
        for (int off = 1; off < 64; off <<= 1) mx = fmaxf(mx, __shfl_xor(mx, off));
        float e = __expf(v - mx);
        float sm = e;
#pragma unroll
        for (int off = 1; off < 64; off <<= 1) sm += __shfl_xor(sm, off);
        float q = e / sm;
        *p = q;
        qs += q;
    }
    red[t] = qs;
    __syncthreads();
    if (w == 0)
        atomicAdd(&Qs[b * K_ + lane], red[lane] + red[64 + lane] + red[128 + lane] + red[192 + lane]);
}

// ---------------- Znum[b,s,k] += sum_{n in chunk} val[b,s,n] * Q[b,n,k]
__global__ __launch_bounds__(256) void znum_acc(
    const float* __restrict__ Val, const float* __restrict__ Q, float* __restrict__ Zn)
{
    __shared__ float vl[S_][33];
    __shared__ float qt[K_][33];  // Q transposed: k x n_sub
    const int b = blockIdx.y;
    const int nc0 = blockIdx.x * 256;
    const int t = threadIdx.x;
    const int lane = t & 63;
    const int k0 = (t >> 6) * 16;
    const int ln = t & 31, lr = t >> 5;
    float acc[4][16];
#pragma unroll
    for (int si = 0; si < 4; ++si)
#pragma unroll
        for (int ki = 0; ki < 16; ++ki) acc[si][ki] = 0.f;

    for (int sub = 0; sub < 8; ++sub) {
        const int n0 = nc0 + sub * 32;
        __syncthreads();
#pragma unroll
        for (int i = 0; i < 32; ++i)
            vl[lr + 8 * i][ln] = Val[((size_t)b * S_ + lr + 8 * i) * N_ + n0 + ln];
        {
            const int k = t & 63;
            const int nb = t >> 6;
#pragma unroll
            for (int i = 0; i < 8; ++i) {
                int nn = nb + 4 * i;
                qt[k][nn] = Q[((size_t)b * N_ + n0 + nn) * K_ + k];
            }
        }
        __syncthreads();
#pragma unroll 4
        for (int n = 0; n < 32; ++n) {
            float tv[4];
#pragma unroll
            for (int si = 0; si < 4; ++si) tv[si] = vl[lane + 64 * si][n];
#pragma unroll
            for (int kg = 0; kg < 4; ++kg) {
                float q0 = qt[k0 + 4 * kg + 0][n];
                float q1 = qt[k0 + 4 * kg + 1][n];
                float q2 = qt[k0 + 4 * kg + 2][n];
                float q3 = qt[k0 + 4 * kg + 3][n];
#pragma unroll
                for (int si = 0; si < 4; ++si) {
                    acc[si][4 * kg + 0] = fmaf(tv[si], q0, acc[si][4 * kg + 0]);
                    acc[si][4 * kg + 1] = fmaf(tv[si], q1, acc[si][4 * kg + 1]);
                    acc[si][4 * kg + 2] = fmaf(tv[si], q2, acc[si][4 * kg + 2]);
                    acc[si][4 * kg + 3] = fmaf(tv[si], q3, acc[si][4 * kg + 3]);
                }
            }
        }
    }
#pragma unroll
    for (int si = 0; si < 4; ++si)
#pragma unroll
        for (int ki = 0; ki < 16; ++ki)
            atomicAdd(&Zn[((size_t)b * S_ + lane + 64 * si) * K_ + k0 + ki], acc[si][ki]);
}

// ---------------- Z = l2norm_s(Znum / qsum)
__global__ __launch_bounds__(256) void z_final(
    const float* __restrict__ Zn, const float* __restrict__ Qs, float* __restrict__ Z)
{
    __shared__ float red[256];
    __shared__ float invn[64];
    const int b = blockIdx.x;
    const int t = threadIdx.x;
    const int lane = t & 63, grp = t >> 6;
    const float invq = 1.0f / Qs[b * K_ + lane];
    float ss = 0.f;
    for (int j = 0; j < 64; ++j) {
        int s = grp * 64 + j;
        float v = Zn[((size_t)b * S_ + s) * K_ + lane] * invq;
        ss = fmaf(v, v, ss);
    }
    red[t] = ss;
    __syncthreads();
    if (grp == 0) {
        float tot = red[lane] + red[64 + lane] + red[128 + lane] + red[192 + lane];
        invn[lane] = 1.0f / fmaxf(sqrtf(tot), 1e-12f);
    }
    __syncthreads();
    const float sc = invq * invn[lane];
    for (int j = 0; j < 64; ++j) {
        int s = grp * 64 + j;
        Z[((size_t)b * S_ + s) * K_ + lane] = Zn[((size_t)b * S_ + s) * K_ + lane] * sc;
    }
}

extern "C" void kernel_launch(void* const* d_in, const int* in_sizes, int n_in,
                              void* d_out, int out_size, void* d_ws, size_t ws_size,
                              hipStream_t stream)
{
    const float* X       = (const float*)d_in[0];
    const float* phi_w   = (const float*)d_in[1];
    const float* phi_g   = (const float*)d_in[2];
    const float* phi_b   = (const float*)d_in[3];
    const float* phi_m   = (const float*)d_in[4];
    const float* phi_v   = (const float*)d_in[5];
    const float* theta_w = (const float*)d_in[6];
    const float* theta_g = (const float*)d_in[7];
    const float* theta_b = (const float*)d_in[8];
    const float* theta_m = (const float*)d_in[9];
    const float* theta_v = (const float*)d_in[10];
    const float* rou_w   = (const float*)d_in[11];
    const float* rou_g   = (const float*)d_in[12];
    const float* rou_b   = (const float*)d_in[13];
    const float* rou_m   = (const float*)d_in[14];
    const float* rou_v   = (const float*)d_in[15];
    const float* val_w   = (const float*)d_in[16];
    const float* val_g   = (const float*)d_in[17];
    const float* val_b   = (const float*)d_in[18];
    const float* val_m   = (const float*)d_in[19];
    const float* val_v   = (const float*)d_in[20];

    float* ws   = (float*)d_ws;
    float* xphi = ws;                                  // B*K*N
    float* xth  = xphi + (size_t)B_ * K_ * N_;         // B*S*N  (theta, later reused for val)
    float* xrou = xth + (size_t)B_ * S_ * N_;          // B*S*N
    float* disc = xrou + (size_t)B_ * S_ * N_;         // B*K*S
    float* nrm2 = disc + (size_t)B_ * K_ * S_;         // B*K
    float* qsum = nrm2 + B_ * K_;                      // B*K
    float* znum = qsum + B_ * K_;                      // B*S*K

    float* Zout = (float*)d_out;                       // B*S*K
    float* Qout = Zout + (size_t)B_ * S_ * K_;         // B*N*K

    // zero all accumulated buffers (disc, nrm2, qsum, znum are contiguous)
    hipMemsetAsync(disc, 0,
        (size_t)(B_ * K_ * S_ + 2 * B_ * K_ + B_ * S_ * K_) * sizeof(float), stream);

    proj_gemm<<<dim3(N_ / 64, 1, B_), 256, 0, stream>>>(X, phi_w, phi_g, phi_b, phi_m, phi_v, xphi, K_);
    proj_gemm<<<dim3(N_ / 64, 4, B_), 256, 0, stream>>>(X, theta_w, theta_g, theta_b, theta_m, theta_v, xth, S_);
    softmax_n<<<B_ * S_, 256, 0, stream>>>(xth);
    discrib_acc<<<dim3(N_ / 256, B_), 256, 0, stream>>>(xphi, xth, disc);
    proj_gemm<<<dim3(N_ / 64, 4, B_), 256, 0, stream>>>(X, rou_w, rou_g, rou_b, rou_m, rou_v, xrou, S_);
    softmax_s<<<dim3(N_ / 256, B_), 256, 0, stream>>>(xrou);
    q_raw<<<dim3(N_ / 256, B_), 256, 0, stream>>>(disc, xrou, Qout);
    q_norm2<<<dim3(N_ / 256, B_), 256, 0, stream>>>(Qout, nrm2);
    q_final<<<dim3(N_ / 256, B_), 256, 0, stream>>>(Qout, nrm2, qsum);
    proj_gemm<<<dim3(N_ / 64, 4, B_), 256, 0, stream>>>(X, val_w, val_g, val_b, val_m, val_v, xth, S_);
    znum_acc<<<dim3(N_ / 256, B_), 256, 0, stream>>>(xth, Qout, znum);
    z_final<<<B_, 256, 0, stream>>>(znum, qsum, Zout);
}

// Round 2
// 949.342 us; speedup vs baseline: 1.3541x; 1.3541x over previous
//
#include <hip/hip_runtime.h>
#include <math.h>

#define B_ 8
#define C_ 256
#define N_ 9216
#define S_ 256
#define K_ 64
#define NCHUNK 36          // 9216 / 256
#define TILE_KS (K_ * S_)  // 16384

// ---------------- fused 1x1conv + BN + ReLU: out[b,o,n] = relu(dot(W[o,:],x[b,:,n])*s + be)
__global__ __launch_bounds__(256) void proj_gemm(
    const float* __restrict__ X, const float* __restrict__ W,
    const float* __restrict__ gg, const float* __restrict__ bb,
    const float* __restrict__ mm, const float* __restrict__ vv,
    float* __restrict__ out, int O)
{
    __shared__ float xs[32][64];   // c x n
    __shared__ float wsT[32][64];  // c x o
    const int b = blockIdx.z;
    const int o0 = blockIdx.y * 64;
    const int n0 = blockIdx.x * 64;
    const int t = threadIdx.x;
    const int tx = t & 15, ty = t >> 4;
    const int nj = t & 63, cb = t >> 6;
    float acc[4][4];
#pragma unroll
    for (int i = 0; i < 4; ++i)
#pragma unroll
        for (int j = 0; j < 4; ++j) acc[i][j] = 0.f;
    const float* Xb = X + (size_t)b * C_ * N_;
    for (int c0 = 0; c0 < C_; c0 += 32) {
#pragma unroll
        for (int k2 = 0; k2 < 8; ++k2) {
            int ci = cb + 4 * k2;
            xs[ci][nj]  = Xb[(size_t)(c0 + ci) * N_ + n0 + nj];
            wsT[ci][nj] = W[(size_t)(o0 + nj) * C_ + c0 + ci];
        }
        __syncthreads();
#pragma unroll
        for (int c = 0; c < 32; ++c) {
            float4 a4 = *(const float4*)&wsT[c][ty * 4];
            float4 b4 = *(const float4*)&xs[c][tx * 4];
            float a[4] = {a4.x, a4.y, a4.z, a4.w};
            float bq[4] = {b4.x, b4.y, b4.z, b4.w};
#pragma unroll
            for (int i = 0; i < 4; ++i)
#pragma unroll
                for (int j = 0; j < 4; ++j)
                    acc[i][j] = fmaf(a[i], bq[j], acc[i][j]);
        }
        __syncthreads();
    }
#pragma unroll
    for (int i = 0; i < 4; ++i) {
        int o = o0 + ty * 4 + i;
        float s  = gg[o] / sqrtf(vv[o] + 1e-5f);
        float be = bb[o] - mm[o] * s;
        float4 r;
        r.x = fmaxf(fmaf(acc[i][0], s, be), 0.f);
        r.y = fmaxf(fmaf(acc[i][1], s, be), 0.f);
        r.z = fmaxf(fmaf(acc[i][2], s, be), 0.f);
        r.w = fmaxf(fmaf(acc[i][3], s, be), 0.f);
        *(float4*)&out[((size_t)b * O + o) * N_ + n0 + tx * 4] = r;
    }
}

// ---------------- softmax over N (rows of length 9216), in place
__global__ __launch_bounds__(256) void softmax_n(float* __restrict__ T)
{
    const int row = blockIdx.x;  // b*S + s
    float* p = T + (size_t)row * N_;
    const int t = threadIdx.x;
    float v[36];
    float mx = -INFINITY;
#pragma unroll
    for (int i = 0; i < 36; ++i) { v[i] = p[t + i * 256]; mx = fmaxf(mx, v[i]); }
    __shared__ float red[256];
    red[t] = mx; __syncthreads();
    for (int s2 = 128; s2 > 0; s2 >>= 1) {
        if (t < s2) red[t] = fmaxf(red[t], red[t + s2]);
        __syncthreads();
    }
    mx = red[0]; __syncthreads();
    float sum = 0.f;
#pragma unroll
    for (int i = 0; i < 36; ++i) { v[i] = __expf(v[i] - mx); sum += v[i]; }
    red[t] = sum; __syncthreads();
    for (int s2 = 128; s2 > 0; s2 >>= 1) {
        if (t < s2) red[t] += red[t + s2];
        __syncthreads();
    }
    float inv = 1.0f / red[0];
#pragma unroll
    for (int i = 0; i < 36; ++i) p[t + i * 256] = v[i] * inv;
}

// ---------------- softmax over S (channels, stride N), in place
__global__ __launch_bounds__(256) void softmax_s(float* __restrict__ R)
{
    const int b = blockIdx.y;
    const int n = blockIdx.x * 256 + threadIdx.x;
    float* p = R + (size_t)b * S_ * N_ + n;
    float mx = -INFINITY;
    for (int s = 0; s < S_; ++s) mx = fmaxf(mx, p[(size_t)s * N_]);
    float sum = 0.f;
    for (int s = 0; s < S_; ++s) sum += __expf(p[(size_t)s * N_] - mx);
    float inv = 1.0f / sum;
    for (int s = 0; s < S_; ++s) p[(size_t)s * N_] = __expf(p[(size_t)s * N_] - mx) * inv;
}

// ---------------- P[chunk][b][k][s] = sum_{n in chunk} A[b,k,n] * Bm[b,s,n]
// (used for discrib: A=phi, Bm=theta; and for znum: A=QTfinal, Bm=val)
__global__ __launch_bounds__(256) void ks_gemm_part(
    const float* __restrict__ A, const float* __restrict__ Bm, float* __restrict__ P)
{
    __shared__ float th[S_][33];
    __shared__ float ph[K_][33];
    const int b = blockIdx.y;
    const int nc0 = blockIdx.x * 256;
    const int t = threadIdx.x;
    const int lane = t & 63;
    const int k0 = (t >> 6) * 16;
    const int ln = t & 31, lr = t >> 5;
    float acc[4][16];
#pragma unroll
    for (int si = 0; si < 4; ++si)
#pragma unroll
        for (int ki = 0; ki < 16; ++ki) acc[si][ki] = 0.f;

    for (int sub = 0; sub < 8; ++sub) {
        const int n0 = nc0 + sub * 32;
        __syncthreads();
#pragma unroll
        for (int i = 0; i < 32; ++i)
            th[lr + 8 * i][ln] = Bm[((size_t)b * S_ + lr + 8 * i) * N_ + n0 + ln];
#pragma unroll
        for (int i = 0; i < 8; ++i)
            ph[lr + 8 * i][ln] = A[((size_t)b * K_ + lr + 8 * i) * N_ + n0 + ln];
        __syncthreads();
#pragma unroll 4
        for (int n = 0; n < 32; ++n) {
            float tv[4];
#pragma unroll
            for (int si = 0; si < 4; ++si) tv[si] = th[lane + 64 * si][n];
#pragma unroll
            for (int kg = 0; kg < 4; ++kg) {
                float p0 = ph[k0 + 4 * kg + 0][n];
                float p1 = ph[k0 + 4 * kg + 1][n];
                float p2 = ph[k0 + 4 * kg + 2][n];
                float p3 = ph[k0 + 4 * kg + 3][n];
#pragma unroll
                for (int si = 0; si < 4; ++si) {
                    acc[si][4 * kg + 0] = fmaf(tv[si], p0, acc[si][4 * kg + 0]);
                    acc[si][4 * kg + 1] = fmaf(tv[si], p1, acc[si][4 * kg + 1]);
                    acc[si][4 * kg + 2] = fmaf(tv[si], p2, acc[si][4 * kg + 2]);
                    acc[si][4 * kg + 3] = fmaf(tv[si], p3, acc[si][4 * kg + 3]);
                }
            }
        }
    }
    float* Pb = P + ((size_t)blockIdx.x * B_ + b) * TILE_KS;
#pragma unroll
    for (int si = 0; si < 4; ++si)
#pragma unroll
        for (int ki = 0; ki < 16; ++ki)
            Pb[(k0 + ki) * S_ + lane + 64 * si] = acc[si][ki];
}

// ---------------- out[i] = sum_c P[c][i]  (i < B_*K_*S_)
__global__ __launch_bounds__(256) void chunk_reduce(
    const float* __restrict__ P, float* __restrict__ out)
{
    const int i = blockIdx.x * 256 + threadIdx.x;
    float s = 0.f;
#pragma unroll
    for (int c = 0; c < NCHUNK; ++c) s += P[(size_t)c * (B_ * TILE_KS) + i];
    out[i] = s;
}

// ---------------- QT[b,k,n] = sum_s D[b,k,s] * rou[b,s,n]
__global__ __launch_bounds__(256) void q_raw(
    const float* __restrict__ D, const float* __restrict__ Rou, float* __restrict__ QT)
{
    __shared__ float dl[K_ * S_];  // 64KB
    const int b = blockIdx.y;
    const int n0 = blockIdx.x * 256;
    const int t = threadIdx.x;
    const float* Db = D + (size_t)b * K_ * S_;
#pragma unroll
    for (int i = 0; i < 64; ++i) dl[t + 256 * i] = Db[t + 256 * i];
    __syncthreads();
    const int n = n0 + t;
    float acc[64];
#pragma unroll
    for (int k = 0; k < 64; ++k) acc[k] = 0.f;
    const float* Rb = Rou + (size_t)b * S_ * N_ + n;
    for (int sg = 0; sg < 64; ++sg) {
        float r0 = Rb[(size_t)(4 * sg + 0) * N_];
        float r1 = Rb[(size_t)(4 * sg + 1) * N_];
        float r2 = Rb[(size_t)(4 * sg + 2) * N_];
        float r3 = Rb[(size_t)(4 * sg + 3) * N_];
#pragma unroll
        for (int k = 0; k < 64; ++k) {
            float4 d4 = *(const float4*)&dl[k * 256 + 4 * sg];
            acc[k] = fmaf(d4.x, r0, fmaf(d4.y, r1, fmaf(d4.z, r2, fmaf(d4.w, r3, acc[k]))));
        }
    }
#pragma unroll
    for (int k = 0; k < 64; ++k)
        QT[((size_t)b * K_ + k) * N_ + n] = acc[k];  // coalesced per k
}

// ---------------- out[row] = sum_n A[row,n] (or sum of squares); row = b*K+k
__global__ __launch_bounds__(256) void row_reduce(
    const float* __restrict__ A, float* __restrict__ out, int squared)
{
    const int row = blockIdx.x;
    const float* p = A + (size_t)row * N_;
    const int t = threadIdx.x;
    float ss = 0.f;
    for (int i = t; i < N_; i += 256) {
        float v = p[i];
        ss = squared ? fmaf(v, v, ss) : (ss + v);
    }
    __shared__ float red[256];
    red[t] = ss; __syncthreads();
    for (int s2 = 128; s2 > 0; s2 >>= 1) {
        if (t < s2) red[t] += red[t + s2];
        __syncthreads();
    }
    if (t == 0) out[row] = red[0];
}

// ---------------- QT = softmax_k(QT / max(sqrt(nrm2),eps)) in place; Qout[b,n,k] transposed copy
__global__ __launch_bounds__(256) void q_final(
    float* __restrict__ QT, const float* __restrict__ Nrm, float* __restrict__ Qout)
{
    __shared__ float T[64][65];
    __shared__ float invn[64];
    const int b = blockIdx.y;
    const int n0 = blockIdx.x * 256;
    const int t = threadIdx.x;
    if (t < 64) invn[t] = 1.0f / fmaxf(sqrtf(Nrm[b * K_ + t]), 1e-12f);
    __syncthreads();
    const int n = n0 + t;
    float q[64];
    float mx = -INFINITY;
#pragma unroll
    for (int k = 0; k < 64; ++k) {
        q[k] = QT[((size_t)b * K_ + k) * N_ + n] * invn[k];
        mx = fmaxf(mx, q[k]);
    }
    float sum = 0.f;
#pragma unroll
    for (int k = 0; k < 64; ++k) { q[k] = __expf(q[k] - mx); sum += q[k]; }
    const float inv = 1.0f / sum;
#pragma unroll
    for (int k = 0; k < 64; ++k) {
        q[k] *= inv;
        QT[((size_t)b * K_ + k) * N_ + n] = q[k];  // coalesced per k
    }
    // transpose 256n x 64k through LDS in 4 groups, coalesced float4 stores
    for (int g = 0; g < 4; ++g) {
        __syncthreads();
        if ((t >> 6) == g) {
#pragma unroll
            for (int k = 0; k < 64; ++k) T[t & 63][k] = q[k];
        }
        __syncthreads();
        float* dst = Qout + ((size_t)b * N_ + n0 + 64 * g) * K_;
#pragma unroll
        for (int j = 0; j < 4; ++j) {
            int p = j * 1024 + t * 4;
            float4 v = *(const float4*)&T[p >> 6][p & 63];
            *(float4*)&dst[p] = v;
        }
    }
}

// ---------------- Z[b,s,k] = l2norm_s(ZnT[b,k,s] / qsum[b,k])
__global__ __launch_bounds__(256) void z_final(
    const float* __restrict__ ZnT, const float* __restrict__ Qs, float* __restrict__ Z)
{
    __shared__ float red[256];
    __shared__ float invn[64];
    const int b = blockIdx.x;
    const int t = threadIdx.x;
    const float* Zb = ZnT + (size_t)b * K_ * S_;
    {
        const int k = t >> 2, qq = t & 3;
        const float invq = 1.0f / Qs[b * K_ + k];
        float ss = 0.f;
        for (int j = 0; j < 64; ++j) {
            float v = Zb[k * S_ + qq * 64 + j] * invq;
            ss = fmaf(v, v, ss);
        }
        red[t] = ss;
    }
    __syncthreads();
    if ((t & 3) == 0) {
        float tot = red[t] + red[t + 1] + red[t + 2] + red[t + 3];
        invn[t >> 2] = 1.0f / fmaxf(sqrtf(tot), 1e-12f);
    }
    __syncthreads();
    {
        const int k = t & 63, w = t >> 6;
        const float sc = invn[k] / Qs[b * K_ + k];
        for (int j = 0; j < 64; ++j) {
            int s = w * 64 + j;
            Z[((size_t)b * S_ + s) * K_ + k] = Zb[k * S_ + s] * sc;  // coalesced per s
        }
    }
}

extern "C" void kernel_launch(void* const* d_in, const int* in_sizes, int n_in,
                              void* d_out, int out_size, void* d_ws, size_t ws_size,
                              hipStream_t stream)
{
    const float* X       = (const float*)d_in[0];
    const float* phi_w   = (const float*)d_in[1];
    const float* phi_g   = (const float*)d_in[2];
    const float* phi_b   = (const float*)d_in[3];
    const float* phi_m   = (const float*)d_in[4];
    const float* phi_v   = (const float*)d_in[5];
    const float* theta_w = (const float*)d_in[6];
    const float* theta_g = (const float*)d_in[7];
    const float* theta_b = (const float*)d_in[8];
    const float* theta_m = (const float*)d_in[9];
    const float* theta_v = (const float*)d_in[10];
    const float* rou_w   = (const float*)d_in[11];
    const float* rou_g   = (const float*)d_in[12];
    const float* rou_b   = (const float*)d_in[13];
    const float* rou_m   = (const float*)d_in[14];
    const float* rou_v   = (const float*)d_in[15];
    const float* val_w   = (const float*)d_in[16];
    const float* val_g   = (const float*)d_in[17];
    const float* val_b   = (const float*)d_in[18];
    const float* val_m   = (const float*)d_in[19];
    const float* val_v   = (const float*)d_in[20];

    float* ws   = (float*)d_ws;
    float* xphi = ws;                                  // B*K*N ; later aliased as QT
    float* xth  = xphi + (size_t)B_ * K_ * N_;         // B*S*N  (theta, later val)
    float* xrou = xth + (size_t)B_ * S_ * N_;          // B*S*N  ; also aliased as partials
    float* disc = xrou + (size_t)B_ * S_ * N_;         // B*K*S
    float* znumT = disc + (size_t)B_ * K_ * S_;        // B*K*S
    float* nrm2 = znumT + (size_t)B_ * K_ * S_;        // B*K
    float* qsum = nrm2 + B_ * K_;                      // B*K

    float* QT   = xphi;   // alias: xphi dead after discrib partials
    float* part = xrou;   // alias: used before xrou written, and after xrou dead

    float* Zout = (float*)d_out;                       // B*S*K
    float* Qout = Zout + (size_t)B_ * S_ * K_;         // B*N*K

    proj_gemm<<<dim3(N_ / 64, 1, B_), 256, 0, stream>>>(X, phi_w, phi_g, phi_b, phi_m, phi_v, xphi, K_);
    proj_gemm<<<dim3(N_ / 64, 4, B_), 256, 0, stream>>>(X, theta_w, theta_g, theta_b, theta_m, theta_v, xth, S_);
    softmax_n<<<B_ * S_, 256, 0, stream>>>(xth);
    ks_gemm_part<<<dim3(NCHUNK, B_), 256, 0, stream>>>(xphi, xth, part);
    chunk_reduce<<<B_ * TILE_KS / 256, 256, 0, stream>>>(part, disc);
    proj_gemm<<<dim3(N_ / 64, 4, B_), 256, 0, stream>>>(X, rou_w, rou_g, rou_b, rou_m, rou_v, xrou, S_);
    softmax_s<<<dim3(N_ / 256, B_), 256, 0, stream>>>(xrou);
    q_raw<<<dim3(N_ / 256, B_), 256, 0, stream>>>(disc, xrou, QT);
    row_reduce<<<B_ * K_, 256, 0, stream>>>(QT, nrm2, 1);
    q_final<<<dim3(N_ / 256, B_), 256, 0, stream>>>(QT, nrm2, Qout);
    row_reduce<<<B_ * K_, 256, 0, stream>>>(QT, qsum, 0);
    proj_gemm<<<dim3(N_ / 64, 4, B_), 256, 0, stream>>>(X, val_w, val_g, val_b, val_m, val_v, xth, S_);
    ks_gemm_part<<<dim3(NCHUNK, B_), 256, 0, stream>>>(QT, xth, part);
    chunk_reduce<<<B_ * TILE_KS / 256, 256, 0, stream>>>(part, znumT);
    z_final<<<B_, 256, 0, stream>>>(znumT, qsum, Zout);
}

// Round 3
// 670.264 us; speedup vs baseline: 1.9178x; 1.4164x over previous
//
#include <hip/hip_runtime.h>
#include <math.h>

#define B_ 8
#define C_ 256
#define N_ 9216
#define S_ 256
#define K_ 64
#define NCHUNK 36          // 9216 / 256
#define TILE_KS (K_ * S_)  // 16384

typedef unsigned short ushort_t;
typedef __attribute__((ext_vector_type(8))) short bf16x8;
typedef __attribute__((ext_vector_type(4))) float f32x4;

static __device__ inline ushort_t f2bf(float x) {
    unsigned int u = __float_as_uint(x);
    unsigned int r = (u + 0x7fffu + ((u >> 16) & 1u)) >> 16;
    return (ushort_t)r;
}

// ---------------- fold BN scale into W, convert to bf16; be[o] = b - m*s
__global__ __launch_bounds__(256) void prep_w(
    const float* __restrict__ phi_w, const float* __restrict__ phi_g, const float* __restrict__ phi_b,
    const float* __restrict__ phi_m, const float* __restrict__ phi_v,
    const float* __restrict__ th_w, const float* __restrict__ th_g, const float* __restrict__ th_b,
    const float* __restrict__ th_m, const float* __restrict__ th_v,
    const float* __restrict__ ro_w, const float* __restrict__ ro_g, const float* __restrict__ ro_b,
    const float* __restrict__ ro_m, const float* __restrict__ ro_v,
    const float* __restrict__ va_w, const float* __restrict__ va_g, const float* __restrict__ va_b,
    const float* __restrict__ va_m, const float* __restrict__ va_v,
    ushort_t* __restrict__ Wb, float* __restrict__ be)
{
    const int o = blockIdx.x;  // 0..831
    const int t = threadIdx.x; // = c
    const float *src, *g, *bb, *mm, *vv; int orel;
    if (o < 64)       { src = phi_w; g = phi_g; bb = phi_b; mm = phi_m; vv = phi_v; orel = o; }
    else if (o < 320) { src = th_w;  g = th_g;  bb = th_b;  mm = th_m;  vv = th_v;  orel = o - 64; }
    else if (o < 576) { src = ro_w;  g = ro_g;  bb = ro_b;  mm = ro_m;  vv = ro_v;  orel = o - 320; }
    else              { src = va_w;  g = va_g;  bb = va_b;  mm = va_m;  vv = va_v;  orel = o - 576; }
    const float s = g[orel] / sqrtf(vv[orel] + 1e-5f);
    Wb[o * C_ + t] = f2bf(src[orel * C_ + t] * s);
    if (t == 0) be[o] = bb[orel] - mm[orel] * s;
}

// ---------------- X[b][c][n] fp32 -> Xb[b][n][c] bf16 (64x64 tiles via LDS)
__global__ __launch_bounds__(256) void xpose(
    const float* __restrict__ X, ushort_t* __restrict__ Xb)
{
    __shared__ float T[64][65];
    const int b = blockIdx.z, c0 = blockIdx.y * 64, n0 = blockIdx.x * 64;
    const int t = threadIdx.x;
#pragma unroll
    for (int p = 0; p < 4; ++p) {
        int c = p * 16 + (t >> 4), nn = (t & 15) * 4;
        float4 v = *(const float4*)&X[((size_t)b * C_ + c0 + c) * N_ + n0 + nn];
        T[c][nn] = v.x; T[c][nn + 1] = v.y; T[c][nn + 2] = v.z; T[c][nn + 3] = v.w;
    }
    __syncthreads();
#pragma unroll
    for (int p = 0; p < 4; ++p) {
        int nn = p * 16 + (t >> 4), cl = (t & 15) * 4;
        ushort4 u;
        u.x = f2bf(T[cl][nn]); u.y = f2bf(T[cl + 1][nn]);
        u.z = f2bf(T[cl + 2][nn]); u.w = f2bf(T[cl + 3][nn]);
        *(ushort4*)&Xb[((size_t)b * N_ + n0 + nn) * C_ + c0 + cl] = u;
    }
}

// ---------------- fused bf16-MFMA projection: out = relu(Wb . x + be)
// block: [64 o] x [256 n]; 4 waves, each [64 o][64 n]; K=256 in 4 stages of 64
__global__ __launch_bounds__(256) void proj_mfma(
    const ushort_t* __restrict__ Wb, const float* __restrict__ be,
    const ushort_t* __restrict__ Xb,
    float* __restrict__ out0, float* __restrict__ out1,
    int phase_base, int o_split, int osz0, int osz1)
{
    __shared__ short sm[32768];  // 64 KB: W cells [0,2048), X cells [2048,4096) (16B cells)
    const int t = threadIdx.x;
    const int l = t & 63, w = t >> 6;
    const int b = blockIdx.x / 36;
    const int n0 = (blockIdx.x % 36) * 256;
    const int o0 = phase_base + blockIdx.y * 64;  // absolute o

    const uint4* Wv = (const uint4*)Wb;
    const uint4* Xv = (const uint4*)Xb;
    uint4* smv = (uint4*)sm;

    // --- stage W (full K) + X stage 0
    uint4 wreg[8], xreg[8];
#pragma unroll
    for (int i = 0; i < 8; ++i) {
        int cell = i * 256 + t;
        int osub = cell >> 9, g = (cell >> 4) & 31, oi = cell & 15;
        wreg[i] = Wv[(size_t)(o0 + osub * 16 + oi) * 32 + g];
    }
#pragma unroll
    for (int i = 0; i < 8; ++i) {
        int cell = i * 256 + t;
        int s = cell >> 7, g8 = (cell >> 4) & 7, ni = cell & 15;
        xreg[i] = Xv[(size_t)(b * N_ + n0 + s * 16 + ni) * 32 + g8];
    }
#pragma unroll
    for (int i = 0; i < 8; ++i) smv[i * 256 + t] = wreg[i];
#pragma unroll
    for (int i = 0; i < 8; ++i) smv[2048 + i * 256 + t] = xreg[i];
    __syncthreads();

    f32x4 zr = {0.f, 0.f, 0.f, 0.f};
    f32x4 acc[4][4];
#pragma unroll
    for (int i = 0; i < 4; ++i)
#pragma unroll
        for (int j = 0; j < 4; ++j) acc[i][j] = zr;

    const bf16x8* smW = (const bf16x8*)sm;
    const bf16x8* smX = (const bf16x8*)(sm + 16384);

    for (int st = 0; st < 4; ++st) {
        if (st < 3) {  // early-issue next stage's global loads (hide under MFMA)
#pragma unroll
            for (int i = 0; i < 8; ++i) {
                int cell = i * 256 + t;
                int s = cell >> 7, g8 = (cell >> 4) & 7, ni = cell & 15;
                xreg[i] = Xv[(size_t)(b * N_ + n0 + s * 16 + ni) * 32 + (st + 1) * 8 + g8];
            }
        }
#pragma unroll
        for (int kgl = 0; kgl < 2; ++kgl) {
            const int kg = st * 2 + kgl;
            bf16x8 A[4], Bf[4];
#pragma unroll
            for (int os = 0; os < 4; ++os)
                A[os] = smW[(os * 32 + kg * 4 + (l >> 4)) * 16 + (l & 15)];
#pragma unroll
            for (int j = 0; j < 4; ++j)
                Bf[j] = smX[((w * 4 + j) * 8 + kgl * 4 + (l >> 4)) * 16 + (l & 15)];
#pragma unroll
            for (int os = 0; os < 4; ++os)
#pragma unroll
                for (int j = 0; j < 4; ++j)
                    acc[os][j] = __builtin_amdgcn_mfma_f32_16x16x32_bf16(A[os], Bf[j], acc[os][j], 0, 0, 0);
        }
        __syncthreads();
        if (st < 3) {
#pragma unroll
            for (int i = 0; i < 8; ++i) smv[2048 + i * 256 + t] = xreg[i];
            __syncthreads();
        }
    }

    // --- epilogue: relu(acc + be), route to output buffer (block-uniform: o_split % 64 == 0)
    const int ob = o0 - phase_base;
    float* dst; int od, osz;
    if (ob < o_split) { dst = out0; od = ob;           osz = osz0; }
    else              { dst = out1; od = ob - o_split; osz = osz1; }
#pragma unroll
    for (int os = 0; os < 4; ++os) {
#pragma unroll
        for (int r = 0; r < 4; ++r) {
            const int orow = os * 16 + (l >> 4) * 4 + r;
            const float bias = be[o0 + orow];
            float* rowp = dst + ((size_t)b * osz + od + orow) * N_ + n0 + w * 64 + (l & 15);
#pragma unroll
            for (int j = 0; j < 4; ++j)
                rowp[j * 16] = fmaxf(acc[os][j][r] + bias, 0.f);
        }
    }
}

// ---------------- softmax over N (rows of length 9216), in place
__global__ __launch_bounds__(256) void softmax_n(float* __restrict__ T)
{
    const int row = blockIdx.x;  // b*S + s
    float* p = T + (size_t)row * N_;
    const int t = threadIdx.x;
    float v[36];
    float mx = -INFINITY;
#pragma unroll
    for (int i = 0; i < 36; ++i) { v[i] = p[t + i * 256]; mx = fmaxf(mx, v[i]); }
    __shared__ float red[256];
    red[t] = mx; __syncthreads();
    for (int s2 = 128; s2 > 0; s2 >>= 1) {
        if (t < s2) red[t] = fmaxf(red[t], red[t + s2]);
        __syncthreads();
    }
    mx = red[0]; __syncthreads();
    float sum = 0.f;
#pragma unroll
    for (int i = 0; i < 36; ++i) { v[i] = __expf(v[i] - mx); sum += v[i]; }
    red[t] = sum; __syncthreads();
    for (int s2 = 128; s2 > 0; s2 >>= 1) {
        if (t < s2) red[t] += red[t + s2];
        __syncthreads();
    }
    float inv = 1.0f / red[0];
#pragma unroll
    for (int i = 0; i < 36; ++i) p[t + i * 256] = v[i] * inv;
}

// ---------------- softmax over S (channels, stride N), in place
__global__ __launch_bounds__(256) void softmax_s(float* __restrict__ R)
{
    const int b = blockIdx.y;
    const int n = blockIdx.x * 256 + threadIdx.x;
    float* p = R + (size_t)b * S_ * N_ + n;
    float mx = -INFINITY;
    for (int s = 0; s < S_; ++s) mx = fmaxf(mx, p[(size_t)s * N_]);
    float sum = 0.f;
    for (int s = 0; s < S_; ++s) sum += __expf(p[(size_t)s * N_] - mx);
    float inv = 1.0f / sum;
    for (int s = 0; s < S_; ++s) p[(size_t)s * N_] = __expf(p[(size_t)s * N_] - mx) * inv;
}

// ---------------- P[chunk][b][k][s] = sum_{n in chunk} A[b,k,n] * Bm[b,s,n]
__global__ __launch_bounds__(256) void ks_gemm_part(
    const float* __restrict__ A, const float* __restrict__ Bm, float* __restrict__ P)
{
    __shared__ float th[S_][33];
    __shared__ float ph[K_][33];
    const int b = blockIdx.y;
    const int nc0 = blockIdx.x * 256;
    const int t = threadIdx.x;
    const int lane = t & 63;
    const int k0 = (t >> 6) * 16;
    const int ln = t & 31, lr = t >> 5;
    float acc[4][16];
#pragma unroll
    for (int si = 0; si < 4; ++si)
#pragma unroll
        for (int ki = 0; ki < 16; ++ki) acc[si][ki] = 0.f;

    for (int sub = 0; sub < 8; ++sub) {
        const int n0 = nc0 + sub * 32;
        __syncthreads();
#pragma unroll
        for (int i = 0; i < 32; ++i)
            th[lr + 8 * i][ln] = Bm[((size_t)b * S_ + lr + 8 * i) * N_ + n0 + ln];
#pragma unroll
        for (int i = 0; i < 8; ++i)
            ph[lr + 8 * i][ln] = A[((size_t)b * K_ + lr + 8 * i) * N_ + n0 + ln];
        __syncthreads();
#pragma unroll 4
        for (int n = 0; n < 32; ++n) {
            float tv[4];
#pragma unroll
            for (int si = 0; si < 4; ++si) tv[si] = th[lane + 64 * si][n];
#pragma unroll
            for (int kg = 0; kg < 4; ++kg) {
                float p0 = ph[k0 + 4 * kg + 0][n];
                float p1 = ph[k0 + 4 * kg + 1][n];
                float p2 = ph[k0 + 4 * kg + 2][n];
                float p3 = ph[k0 + 4 * kg + 3][n];
#pragma unroll
                for (int si = 0; si < 4; ++si) {
                    acc[si][4 * kg + 0] = fmaf(tv[si], p0, acc[si][4 * kg + 0]);
                    acc[si][4 * kg + 1] = fmaf(tv[si], p1, acc[si][4 * kg + 1]);
                    acc[si][4 * kg + 2] = fmaf(tv[si], p2, acc[si][4 * kg + 2]);
                    acc[si][4 * kg + 3] = fmaf(tv[si], p3, acc[si][4 * kg + 3]);
                }
            }
        }
    }
    float* Pb = P + ((size_t)blockIdx.x * B_ + b) * TILE_KS;
#pragma unroll
    for (int si = 0; si < 4; ++si)
#pragma unroll
        for (int ki = 0; ki < 16; ++ki)
            Pb[(k0 + ki) * S_ + lane + 64 * si] = acc[si][ki];
}

// ---------------- out[i] = sum_c P[c][i]
__global__ __launch_bounds__(256) void chunk_reduce(
    const float* __restrict__ P, float* __restrict__ out)
{
    const int i = blockIdx.x * 256 + threadIdx.x;
    float s = 0.f;
#pragma unroll
    for (int c = 0; c < NCHUNK; ++c) s += P[(size_t)c * (B_ * TILE_KS) + i];
    out[i] = s;
}

// ---------------- QT[b,k,n] = sum_s D[b,k,s] * rou[b,s,n]
__global__ __launch_bounds__(256) void q_raw(
    const float* __restrict__ D, const float* __restrict__ Rou, float* __restrict__ QT)
{
    __shared__ float dl[K_ * S_];  // 64KB
    const int b = blockIdx.y;
    const int n0 = blockIdx.x * 256;
    const int t = threadIdx.x;
    const float* Db = D + (size_t)b * K_ * S_;
#pragma unroll
    for (int i = 0; i < 64; ++i) dl[t + 256 * i] = Db[t + 256 * i];
    __syncthreads();
    const int n = n0 + t;
    float acc[64];
#pragma unroll
    for (int k = 0; k < 64; ++k) acc[k] = 0.f;
    const float* Rb = Rou + (size_t)b * S_ * N_ + n;
    for (int sg = 0; sg < 64; ++sg) {
        float r0 = Rb[(size_t)(4 * sg + 0) * N_];
        float r1 = Rb[(size_t)(4 * sg + 1) * N_];
        float r2 = Rb[(size_t)(4 * sg + 2) * N_];
        float r3 = Rb[(size_t)(4 * sg + 3) * N_];
#pragma unroll
        for (int k = 0; k < 64; ++k) {
            float4 d4 = *(const float4*)&dl[k * 256 + 4 * sg];
            acc[k] = fmaf(d4.x, r0, fmaf(d4.y, r1, fmaf(d4.z, r2, fmaf(d4.w, r3, acc[k]))));
        }
    }
#pragma unroll
    for (int k = 0; k < 64; ++k)
        QT[((size_t)b * K_ + k) * N_ + n] = acc[k];
}

// ---------------- out[row] = sum_n A[row,n] (or sum of squares)
__global__ __launch_bounds__(256) void row_reduce(
    const float* __restrict__ A, float* __restrict__ out, int squared)
{
    const int row = blockIdx.x;
    const float* p = A + (size_t)row * N_;
    const int t = threadIdx.x;
    float ss = 0.f;
    for (int i = t; i < N_; i += 256) {
        float v = p[i];
        ss = squared ? fmaf(v, v, ss) : (ss + v);
    }
    __shared__ float red[256];
    red[t] = ss; __syncthreads();
    for (int s2 = 128; s2 > 0; s2 >>= 1) {
        if (t < s2) red[t] += red[t + s2];
        __syncthreads();
    }
    if (t == 0) out[row] = red[0];
}

// ---------------- QT = softmax_k(QT / max(sqrt(nrm2),eps)) in place; Qout[b,n,k] transposed copy
__global__ __launch_bounds__(256) void q_final(
    float* __restrict__ QT, const float* __restrict__ Nrm, float* __restrict__ Qout)
{
    __shared__ float T[64][65];
    __shared__ float invn[64];
    const int b = blockIdx.y;
    const int n0 = blockIdx.x * 256;
    const int t = threadIdx.x;
    if (t < 64) invn[t] = 1.0f / fmaxf(sqrtf(Nrm[b * K_ + t]), 1e-12f);
    __syncthreads();
    const int n = n0 + t;
    float q[64];
    float mx = -INFINITY;
#pragma unroll
    for (int k = 0; k < 64; ++k) {
        q[k] = QT[((size_t)b * K_ + k) * N_ + n] * invn[k];
        mx = fmaxf(mx, q[k]);
    }
    float sum = 0.f;
#pragma unroll
    for (int k = 0; k < 64; ++k) { q[k] = __expf(q[k] - mx); sum += q[k]; }
    const float inv = 1.0f / sum;
#pragma unroll
    for (int k = 0; k < 64; ++k) {
        q[k] *= inv;
        QT[((size_t)b * K_ + k) * N_ + n] = q[k];
    }
    for (int g = 0; g < 4; ++g) {
        __syncthreads();
        if ((t >> 6) == g) {
#pragma unroll
            for (int k = 0; k < 64; ++k) T[t & 63][k] = q[k];
        }
        __syncthreads();
        float* dst = Qout + ((size_t)b * N_ + n0 + 64 * g) * K_;
#pragma unroll
        for (int j = 0; j < 4; ++j) {
            int p = j * 1024 + t * 4;
            float4 v = *(const float4*)&T[p >> 6][p & 63];
            *(float4*)&dst[p] = v;
        }
    }
}

// ---------------- Z[b,s,k] = l2norm_s(ZnT[b,k,s] / qsum[b,k])
__global__ __launch_bounds__(256) void z_final(
    const float* __restrict__ ZnT, const float* __restrict__ Qs, float* __restrict__ Z)
{
    __shared__ float red[256];
    __shared__ float invn[64];
    const int b = blockIdx.x;
    const int t = threadIdx.x;
    const float* Zb = ZnT + (size_t)b * K_ * S_;
    {
        const int k = t >> 2, qq = t & 3;
        const float invq = 1.0f / Qs[b * K_ + k];
        float ss = 0.f;
        for (int j = 0; j < 64; ++j) {
            float v = Zb[k * S_ + qq * 64 + j] * invq;
            ss = fmaf(v, v, ss);
        }
        red[t] = ss;
    }
    __syncthreads();
    if ((t & 3) == 0) {
        float tot = red[t] + red[t + 1] + red[t + 2] + red[t + 3];
        invn[t >> 2] = 1.0f / fmaxf(sqrtf(tot), 1e-12f);
    }
    __syncthreads();
    {
        const int k = t & 63, w = t >> 6;
        const float sc = invn[k] / Qs[b * K_ + k];
        for (int j = 0; j < 64; ++j) {
            int s = w * 64 + j;
            Z[((size_t)b * S_ + s) * K_ + k] = Zb[k * S_ + s] * sc;
        }
    }
}

extern "C" void kernel_launch(void* const* d_in, const int* in_sizes, int n_in,
                              void* d_out, int out_size, void* d_ws, size_t ws_size,
                              hipStream_t stream)
{
    const float* X       = (const float*)d_in[0];
    const float* phi_w   = (const float*)d_in[1];
    const float* phi_g   = (const float*)d_in[2];
    const float* phi_b   = (const float*)d_in[3];
    const float* phi_m   = (const float*)d_in[4];
    const float* phi_v   = (const float*)d_in[5];
    const float* theta_w = (const float*)d_in[6];
    const float* theta_g = (const float*)d_in[7];
    const float* theta_b = (const float*)d_in[8];
    const float* theta_m = (const float*)d_in[9];
    const float* theta_v = (const float*)d_in[10];
    const float* rou_w   = (const float*)d_in[11];
    const float* rou_g   = (const float*)d_in[12];
    const float* rou_b   = (const float*)d_in[13];
    const float* rou_m   = (const float*)d_in[14];
    const float* rou_v   = (const float*)d_in[15];
    const float* val_w   = (const float*)d_in[16];
    const float* val_g   = (const float*)d_in[17];
    const float* val_b   = (const float*)d_in[18];
    const float* val_m   = (const float*)d_in[19];
    const float* val_v   = (const float*)d_in[20];

    float* ws = (float*)d_ws;
    size_t off = 0;
    ushort_t* Xb = (ushort_t*)(ws + off); off += (size_t)B_ * N_ * C_ / 2;   // bf16 [b][n][c]
    ushort_t* Wb = (ushort_t*)(ws + off); off += 832 * C_ / 2;               // bf16 [832][256]
    float* be   = ws + off; off += 832;
    float* xphi = ws + off; off += (size_t)B_ * K_ * N_;    // phi; later QT alias
    float* xth  = ws + off; off += (size_t)B_ * S_ * N_;    // theta; later val
    float* xrou = ws + off; off += (size_t)B_ * S_ * N_;
    float* part = ws + off; off += (size_t)NCHUNK * B_ * TILE_KS;
    float* disc = ws + off; off += (size_t)B_ * K_ * S_;
    float* znumT= ws + off; off += (size_t)B_ * K_ * S_;
    float* nrm2 = ws + off; off += B_ * K_;
    float* qsum = ws + off; off += B_ * K_;

    float* QT = xphi;

    float* Zout = (float*)d_out;                       // B*S*K
    float* Qout = Zout + (size_t)B_ * S_ * K_;         // B*N*K

    prep_w<<<832, 256, 0, stream>>>(phi_w, phi_g, phi_b, phi_m, phi_v,
                                    theta_w, theta_g, theta_b, theta_m, theta_v,
                                    rou_w, rou_g, rou_b, rou_m, rou_v,
                                    val_w, val_g, val_b, val_m, val_v, Wb, be);
    xpose<<<dim3(N_ / 64, C_ / 64, B_), 256, 0, stream>>>(X, Xb);

    // phase A: o in [0,320): phi (64 rows) + theta (256 rows)
    proj_mfma<<<dim3(36 * B_, 5), 256, 0, stream>>>(Wb, be, Xb, xphi, xth, 0, 64, K_, S_);
    softmax_n<<<B_ * S_, 256, 0, stream>>>(xth);
    ks_gemm_part<<<dim3(NCHUNK, B_), 256, 0, stream>>>(xphi, xth, part);
    chunk_reduce<<<B_ * TILE_KS / 256, 256, 0, stream>>>(part, disc);

    // phase B: o in [320,832): rou (256 rows) + val (256 rows, into xth)
    proj_mfma<<<dim3(36 * B_, 8), 256, 0, stream>>>(Wb, be, Xb, xrou, xth, 320, 256, S_, S_);
    softmax_s<<<dim3(N_ / 256, B_), 256, 0, stream>>>(xrou);
    q_raw<<<dim3(N_ / 256, B_), 256, 0, stream>>>(disc, xrou, QT);
    row_reduce<<<B_ * K_, 256, 0, stream>>>(QT, nrm2, 1);
    q_final<<<dim3(N_ / 256, B_), 256, 0, stream>>>(QT, nrm2, Qout);
    row_reduce<<<B_ * K_, 256, 0, stream>>>(QT, qsum, 0);
    ks_gemm_part<<<dim3(NCHUNK, B_), 256, 0, stream>>>(QT, xth, part);
    chunk_reduce<<<B_ * TILE_KS / 256, 256, 0, stream>>>(part, znumT);
    z_final<<<B_, 256, 0, stream>>>(znumT, qsum, Zout);
}